// Round 5
// baseline (852.968 us; speedup 1.0000x reference)
//
#include <hip/hip_runtime.h>

#define ATOMF 82
#define EDGE_DIM 6
#define HIDDEN 10
#define ZPAD 16  // z row = 10 bf16 + 6 pad = 32 B

// bucketed CSR build parameters
#define BSHIFT 8          // 256 nodes per bucket
#define BUCKN (1 << BSHIFT)
#define MAXBUCK 1024      // fast path supports n_nodes <= 262144 (and <= 2^24 for packing)
#define NB2 256           // partition blocks: open write-lines/XCD ~ 1.6MB < 4MB L2
#define MAXE3 16384       // per-bucket edge capacity for LDS lid cache

__device__ __forceinline__ float lrelu(float x) { return x > 0.f ? x : 0.1f * x; }

__device__ __forceinline__ unsigned int f2bf(float f) {
    unsigned int u = __float_as_uint(f);
    return (u + 0x7fffu + ((u >> 16) & 1u)) >> 16;  // RNE
}
__device__ __forceinline__ float bf2f(unsigned int b) {
    return __uint_as_float(b << 16);
}

// h[node] = lrelu(vertex[node] @ W); z[node] = bf16(h[node] @ GW_h)
__global__ void embed_kernel(const float* __restrict__ vertex,
                             const float* __restrict__ W,
                             const float* __restrict__ GW,
                             float* __restrict__ h, unsigned short* __restrict__ z,
                             int n_nodes) {
    __shared__ float w[ATOMF * HIDDEN];
    __shared__ float gwh[HIDDEN * HIDDEN];
    for (int i = threadIdx.x; i < ATOMF * HIDDEN; i += blockDim.x) w[i] = W[i];
    for (int i = threadIdx.x; i < HIDDEN * HIDDEN; i += blockDim.x) gwh[i] = GW[i];
    __syncthreads();
    int node = blockIdx.x * blockDim.x + threadIdx.x;
    if (node >= n_nodes) return;
    const float2* v = (const float2*)(vertex + (long)node * ATOMF);  // 328B rows, 8B aligned
    float acc[HIDDEN];
#pragma unroll
    for (int j = 0; j < HIDDEN; j++) acc[j] = 0.f;
#pragma unroll 2
    for (int k2 = 0; k2 < ATOMF / 2; k2++) {
        float2 t = v[k2];
#pragma unroll
        for (int j = 0; j < HIDDEN; j++) acc[j] += t.x * w[(2 * k2) * HIDDEN + j];
#pragma unroll
        for (int j = 0; j < HIDDEN; j++) acc[j] += t.y * w[(2 * k2 + 1) * HIDDEN + j];
    }
    float ho[HIDDEN];
    float* out = h + (long)node * HIDDEN;
#pragma unroll
    for (int j = 0; j < HIDDEN; j++) { ho[j] = lrelu(acc[j]); out[j] = ho[j]; }
    float zv[HIDDEN];
#pragma unroll
    for (int j = 0; j < HIDDEN; j++) zv[j] = 0.f;
#pragma unroll
    for (int k = 0; k < HIDDEN; k++) {
        float x = ho[k];
#pragma unroll
        for (int j = 0; j < HIDDEN; j++) zv[j] += x * gwh[k * HIDDEN + j];
    }
    unsigned int* zq = (unsigned int*)(z + (size_t)node * ZPAD);
    int4 pk;
    pk.x = (int)(f2bf(zv[0]) | (f2bf(zv[1]) << 16));
    pk.y = (int)(f2bf(zv[2]) | (f2bf(zv[3]) << 16));
    pk.z = (int)(f2bf(zv[4]) | (f2bf(zv[5]) << 16));
    pk.w = (int)(f2bf(zv[6]) | (f2bf(zv[7]) << 16));
    *(int4*)zq = pk;
    zq[4] = f2bf(zv[8]) | (f2bf(zv[9]) << 16);
}

// ---- P1: per-(bucket,block) histogram, LDS atomics only ----
__global__ __launch_bounds__(512) void hist_kernel(const int* __restrict__ dst,
                                                   int* __restrict__ hist,
                                                   long n_edges, int nbuck) {
    __shared__ int hl[MAXBUCK];
    for (int t = threadIdx.x; t < nbuck; t += 512) hl[t] = 0;
    __syncthreads();
    long per = (n_edges + gridDim.x - 1) / gridDim.x;
    long s = (long)blockIdx.x * per;
    long e = s + per; if (e > n_edges) e = n_edges;
    for (long i = s + threadIdx.x; i < e; i += 512)
        atomicAdd(&hl[dst[i] >> BSHIFT], 1);
    __syncthreads();
    for (int t = threadIdx.x; t < nbuck; t += 512)
        hist[(size_t)t * gridDim.x + blockIdx.x] = hl[t];
}

// ---- generic device-wide exclusive scan: in[0..n-1] -> out[0..n] ----
__global__ __launch_bounds__(1024) void scan_block_sums(const int* __restrict__ in,
                                                        int* __restrict__ partials, int n) {
    __shared__ int ws[16];
    int i = blockIdx.x * 1024 + threadIdx.x;
    int v = (i < n) ? in[i] : 0;
    int lane = threadIdx.x & 63, wid = threadIdx.x >> 6;
    int s = v;
#pragma unroll
    for (int off = 32; off > 0; off >>= 1) s += __shfl_down(s, off, 64);
    if (lane == 0) ws[wid] = s;
    __syncthreads();
    if (threadIdx.x == 0) {
        int t = 0;
#pragma unroll
        for (int k = 0; k < 16; k++) t += ws[k];
        partials[blockIdx.x] = t;
    }
}
__global__ __launch_bounds__(1024) void scan_partials(int* __restrict__ partials, int nb) {
    __shared__ int wsum[16];
    int lane = threadIdx.x & 63, wid = threadIdx.x >> 6;
    int v = (threadIdx.x < nb) ? partials[threadIdx.x] : 0;
    int incl = v;
#pragma unroll
    for (int off = 1; off < 64; off <<= 1) {
        int t = __shfl_up(incl, off, 64);
        if (lane >= off) incl += t;
    }
    if (lane == 63) wsum[wid] = incl;
    __syncthreads();
    if (wid == 0 && lane < 16) {
        int wv = wsum[lane];
        int wincl = wv;
#pragma unroll
        for (int off = 1; off < 16; off <<= 1) {
            int t = __shfl_up(wincl, off, 64);
            if (lane >= off) wincl += t;
        }
        wsum[lane] = wincl - wv;
    }
    __syncthreads();
    if (threadIdx.x < nb) partials[threadIdx.x] = wsum[wid] + (incl - v);
}
__global__ __launch_bounds__(1024) void scan_final(const int* __restrict__ in,
                                                   const int* __restrict__ partials,
                                                   int* __restrict__ out, int n) {
    __shared__ int wsum[16];
    int i = blockIdx.x * 1024 + threadIdx.x;
    int v = (i < n) ? in[i] : 0;
    int lane = threadIdx.x & 63, wid = threadIdx.x >> 6;
    int incl = v;
#pragma unroll
    for (int off = 1; off < 64; off <<= 1) {
        int t = __shfl_up(incl, off, 64);
        if (lane >= off) incl += t;
    }
    if (lane == 63) wsum[wid] = incl;
    __syncthreads();
    if (wid == 0 && lane < 16) {
        int wv = wsum[lane];
        int wincl = wv;
#pragma unroll
        for (int off = 1; off < 16; off <<= 1) {
            int t = __shfl_up(wincl, off, 64);
            if (lane >= off) wincl += t;
        }
        wsum[lane] = wincl - wv;
    }
    __syncthreads();
    if (i <= n) out[i] = partials[blockIdx.x] + wsum[wid] + (incl - v);
}

// ---- P2: partition edges into bucket-grouped order; LDS cursor atomics only.
// 4 consecutive edges per thread per iteration for ILP (int4 dst/src loads,
// 96B contiguous ef reads). Node-local id packed into r.x[31:24] (n_nodes <= 2^24).
__global__ __launch_bounds__(512) void part_scatter_kernel(
    const int* __restrict__ src, const int* __restrict__ dst,
    const float* __restrict__ ef, const int* __restrict__ base,
    int4* __restrict__ rec, long n_edges, int nbuck) {
    __shared__ int cur[MAXBUCK];
    for (int t = threadIdx.x; t < nbuck; t += 512)
        cur[t] = base[(size_t)t * gridDim.x + blockIdx.x];
    __syncthreads();
    long per = ((n_edges + gridDim.x - 1) / gridDim.x + 3) & ~3L;  // 4-aligned chunks
    long s = (long)blockIdx.x * per;
    long e = s + per; if (e > n_edges) e = n_edges;
    for (long i0 = s + (long)threadIdx.x * 4; i0 < e; i0 += 512 * 4) {
        if (i0 + 3 < e) {
            int4 d4 = *(const int4*)(dst + i0);
            int4 s4 = *(const int4*)(src + i0);
            int dd[4] = {d4.x, d4.y, d4.z, d4.w};
            int ss[4] = {s4.x, s4.y, s4.z, s4.w};
            int slot[4];
#pragma unroll
            for (int k = 0; k < 4; k++)
                slot[k] = atomicAdd(&cur[dd[k] >> BSHIFT], 1);  // LDS atomic
#pragma unroll
            for (int k = 0; k < 4; k++) {
                const float2* er = (const float2*)(ef + (i0 + k) * (long)EDGE_DIM);
                float2 fa = er[0], fb = er[1], fc = er[2];
                int4 r;
                r.x = ss[k] | ((dd[k] & (BUCKN - 1)) << 24);
                r.y = (int)(f2bf(fa.x) | (f2bf(fa.y) << 16));
                r.z = (int)(f2bf(fb.x) | (f2bf(fb.y) << 16));
                r.w = (int)(f2bf(fc.x) | (f2bf(fc.y) << 16));
                rec[slot[k]] = r;
            }
        } else {
            for (long i = i0; i < e; i++) {
                int d = dst[i];
                int slot = atomicAdd(&cur[d >> BSHIFT], 1);
                const float2* er = (const float2*)(ef + i * (long)EDGE_DIM);
                float2 fa = er[0], fb = er[1], fc = er[2];
                int4 r;
                r.x = src[i] | ((d & (BUCKN - 1)) << 24);
                r.y = (int)(f2bf(fa.x) | (f2bf(fa.y) << 16));
                r.z = (int)(f2bf(fb.x) | (f2bf(fb.y) << 16));
                r.w = (int)(f2bf(fc.x) | (f2bf(fc.y) << 16));
                rec[slot] = r;
            }
        }
    }
}

// ---- P3: per-bucket node sort: count+scan in LDS, permute rec_a -> rec_b (keeps
// packed l byte), write per-node offsets. Bucket span ~128KB -> permute re-read is L2-hit.
__global__ __launch_bounds__(256) void bucket_csr_kernel(
    const int* __restrict__ base, const int4* __restrict__ rec_a, int4* __restrict__ rec_b,
    int* __restrict__ offsets, int n_nodes) {
    __shared__ unsigned char lid[MAXE3];
    __shared__ int cnt[BUCKN];
    __shared__ int excl_s[BUCKN];
    __shared__ int cursor[BUCKN];
    int b = blockIdx.x;
    int S = base[(size_t)b * NB2];
    int E = base[(size_t)(b + 1) * NB2];
    int node0 = b << BSHIFT;
    int nn = n_nodes - node0; if (nn > BUCKN) nn = BUCKN;
    cnt[threadIdx.x] = 0;
    __syncthreads();
    int ne = E - S;
    bool fit = (ne <= MAXE3);
    for (int i = threadIdx.x; i < ne; i += 256) {
        int l = (int)((unsigned int)rec_a[S + i].x >> 24);
        if (fit) lid[i] = (unsigned char)l;
        atomicAdd(&cnt[l], 1);
    }
    __syncthreads();
    if (threadIdx.x == 0) {
        int run = 0;
#pragma unroll 4
        for (int l = 0; l < BUCKN; l++) { excl_s[l] = run; run += cnt[l]; }
    }
    __syncthreads();
    if ((int)threadIdx.x < nn) offsets[node0 + threadIdx.x] = S + excl_s[threadIdx.x];
    cursor[threadIdx.x] = excl_s[threadIdx.x];
    if (b == (int)gridDim.x - 1 && threadIdx.x == 0) offsets[n_nodes] = E;
    __syncthreads();
    for (int i = threadIdx.x; i < ne; i += 256) {
        int4 r = rec_a[S + i];  // L2-resident re-read
        int l = fit ? (int)lid[i] : (int)((unsigned int)r.x >> 24);
        int q = atomicAdd(&cursor[l], 1);  // LDS atomic
        rec_b[S + q] = r;
    }
}

// ---- fallback path (small workspace / huge n_nodes): global-atomic rank ----
__global__ void count_pos_kernel(const int* __restrict__ dst, int* __restrict__ counts,
                                 unsigned short* __restrict__ pos, long n_edges) {
    long e0 = ((long)blockIdx.x * blockDim.x + threadIdx.x) * 4;
    if (e0 + 3 < n_edges) {
        int4 d = *(const int4*)(dst + e0);
        ushort4 p;
        p.x = (unsigned short)atomicAdd(&counts[d.x], 1);
        p.y = (unsigned short)atomicAdd(&counts[d.y], 1);
        p.z = (unsigned short)atomicAdd(&counts[d.z], 1);
        p.w = (unsigned short)atomicAdd(&counts[d.w], 1);
        *(ushort4*)(pos + e0) = p;
    } else {
        for (long e = e0; e < n_edges; e++)
            pos[e] = (unsigned short)atomicAdd(&counts[dst[e]], 1);
    }
}
__global__ void scatter_rec_kernel(const int* __restrict__ src, const int* __restrict__ dst,
                                   const float* __restrict__ ef,
                                   const unsigned short* __restrict__ pos,
                                   const int* __restrict__ offsets,
                                   int4* __restrict__ rec, long n_edges) {
    long e = (long)blockIdx.x * blockDim.x + threadIdx.x;
    if (e >= n_edges) return;
    int d = dst[e];
    int q = offsets[d] + (int)pos[e];
    const float2* er = (const float2*)(ef + e * (long)EDGE_DIM);
    float2 fa = er[0], fb = er[1], fc = er[2];
    int4 r;
    r.x = src[e];
    r.y = (int)(f2bf(fa.x) | (f2bf(fa.y) << 16));
    r.z = (int)(f2bf(fb.x) | (f2bf(fb.y) << 16));
    r.w = (int)(f2bf(fc.x) | (f2bf(fc.y) << 16));
    rec[q] = r;
}

// ---- gather+update: ONE LANE PER NODE, batch-4 record pipeline.
// Each lane streams its node's sorted records in batches of 4: 4 rec loads
// (lane-local contiguous 64B line) + 8 z loads issued together -> 12 outstanding
// loads/lane to hide L3/HBM gather latency. Epilogue GEMV runs on all 64 lanes.
__global__ __launch_bounds__(256) void gather_update_kernel(
    const float* __restrict__ h_in, const unsigned short* __restrict__ z_in,
    const int4* __restrict__ rec, const int* __restrict__ offsets,
    const float* __restrict__ GW, const float* __restrict__ UW,
    float* __restrict__ h_out, unsigned short* __restrict__ z_out,
    int n_nodes, int write_z, unsigned int src_mask) {
    __shared__ float gwh[HIDDEN * HIDDEN];    // GW rows 0..9  (h part)
    __shared__ float gwe[EDGE_DIM * HIDDEN];  // GW rows 10..15 (ef part)
    __shared__ float uw[2 * HIDDEN * HIDDEN];
    for (int i = threadIdx.x; i < HIDDEN * HIDDEN; i += 256) gwh[i] = GW[i];
    for (int i = threadIdx.x; i < EDGE_DIM * HIDDEN; i += 256) gwe[i] = GW[HIDDEN * HIDDEN + i];
    for (int i = threadIdx.x; i < 2 * HIDDEN * HIDDEN; i += 256) uw[i] = UW[i];
    __syncthreads();
    int node = blockIdx.x * 256 + threadIdx.x;
    if (node >= n_nodes) return;
    int off0 = offsets[node], off1 = offsets[node + 1];
    float acc[HIDDEN];
#pragma unroll
    for (int j = 0; j < HIDDEN; j++) acc[j] = 0.f;
    for (int p = off0; p < off1; p += 4) {
        int nb = off1 - p;  // >= 1
        int4 r[4];
#pragma unroll
        for (int k = 0; k < 4; k++) if (k < nb) r[k] = rec[p + k];
        int4 za[4]; int zb[4];
#pragma unroll
        for (int k = 0; k < 4; k++) if (k < nb) {
            const int* zq = (const int*)(z_in +
                (size_t)((unsigned int)r[k].x & src_mask) * ZPAD);
            za[k] = *(const int4*)zq;
            zb[k] = zq[4];
        }
#pragma unroll
        for (int k = 0; k < 4; k++) if (k < nb) {
            float ef[EDGE_DIM];
            unsigned int u0 = (unsigned int)r[k].y, u1 = (unsigned int)r[k].z,
                         u2 = (unsigned int)r[k].w;
            ef[0] = bf2f(u0 & 0xffffu); ef[1] = bf2f(u0 >> 16);
            ef[2] = bf2f(u1 & 0xffffu); ef[3] = bf2f(u1 >> 16);
            ef[4] = bf2f(u2 & 0xffffu); ef[5] = bf2f(u2 >> 16);
            float m[HIDDEN];
#pragma unroll
            for (int j = 0; j < HIDDEN; j++) m[j] = 0.f;
#pragma unroll
            for (int kk = 0; kk < EDGE_DIM; kk++) {
                float x = ef[kk];
#pragma unroll
                for (int j = 0; j < HIDDEN; j++) m[j] += x * gwe[kk * HIDDEN + j];
            }
            unsigned int z0 = (unsigned int)za[k].x, z1 = (unsigned int)za[k].y;
            unsigned int z2 = (unsigned int)za[k].z, z3 = (unsigned int)za[k].w;
            unsigned int z4 = (unsigned int)zb[k];
            acc[0] += lrelu(m[0] + bf2f(z0 & 0xffffu));
            acc[1] += lrelu(m[1] + bf2f(z0 >> 16));
            acc[2] += lrelu(m[2] + bf2f(z1 & 0xffffu));
            acc[3] += lrelu(m[3] + bf2f(z1 >> 16));
            acc[4] += lrelu(m[4] + bf2f(z2 & 0xffffu));
            acc[5] += lrelu(m[5] + bf2f(z2 >> 16));
            acc[6] += lrelu(m[6] + bf2f(z3 & 0xffffu));
            acc[7] += lrelu(m[7] + bf2f(z3 >> 16));
            acc[8] += lrelu(m[8] + bf2f(z4 & 0xffffu));
            acc[9] += lrelu(m[9] + bf2f(z4 >> 16));
        }
    }
    // epilogue: all lanes active, coalesced h_in/h_out/z_out
    float in[2 * HIDDEN];
    const float2* hp = (const float2*)(h_in + (size_t)node * HIDDEN);
#pragma unroll
    for (int k = 0; k < 5; k++) { float2 t = hp[k]; in[2 * k] = t.x; in[2 * k + 1] = t.y; }
#pragma unroll
    for (int j = 0; j < HIDDEN; j++) in[HIDDEN + j] = acc[j];
    float o[HIDDEN];
#pragma unroll
    for (int j = 0; j < HIDDEN; j++) o[j] = 0.f;
#pragma unroll
    for (int k = 0; k < 2 * HIDDEN; k++) {
        float x = in[k];
#pragma unroll
        for (int j = 0; j < HIDDEN; j++) o[j] += x * uw[k * HIDDEN + j];
    }
    float ho[HIDDEN];
    float* outp = h_out + (size_t)node * HIDDEN;
#pragma unroll
    for (int j = 0; j < HIDDEN; j++) { ho[j] = lrelu(o[j]); outp[j] = ho[j]; }
    if (write_z) {
        float zv[HIDDEN];
#pragma unroll
        for (int j = 0; j < HIDDEN; j++) zv[j] = 0.f;
#pragma unroll
        for (int k = 0; k < HIDDEN; k++) {
            float x = ho[k];
#pragma unroll
            for (int j = 0; j < HIDDEN; j++) zv[j] += x * gwh[k * HIDDEN + j];
        }
        unsigned int* zq = (unsigned int*)(z_out + (size_t)node * ZPAD);
        int4 pk;
        pk.x = (int)(f2bf(zv[0]) | (f2bf(zv[1]) << 16));
        pk.y = (int)(f2bf(zv[2]) | (f2bf(zv[3]) << 16));
        pk.z = (int)(f2bf(zv[4]) | (f2bf(zv[5]) << 16));
        pk.w = (int)(f2bf(zv[6]) | (f2bf(zv[7]) << 16));
        *(int4*)zq = pk;
        zq[4] = f2bf(zv[8]) | (f2bf(zv[9]) << 16);
    }
}

extern "C" void kernel_launch(void* const* d_in, const int* in_sizes, int n_in,
                              void* d_out, int out_size, void* d_ws, size_t ws_size,
                              hipStream_t stream) {
    const float* vertex    = (const float*)d_in[0];
    const float* edge_feat = (const float*)d_in[1];
    const int*   src       = (const int*)d_in[2];
    const int*   dst       = (const int*)d_in[3];
    const float* w_init    = (const float*)d_in[4];
    const float* gw        = (const float*)d_in[5];
    const float* uw        = (const float*)d_in[6];

    const int  n_nodes = in_sizes[0] / ATOMF;
    const long n_edges = (long)in_sizes[2];
    float* out = (float*)d_out;

    const int TB = 256;
    const int node_blocks = (n_nodes + TB - 1) / TB;
    const int gu_blocks   = (n_nodes + 255) / 256;

    const int nbuck = (n_nodes + BUCKN - 1) >> BSHIFT;
    const long m = (long)nbuck * NB2;
    const int scanb_m = (int)((m + 1 + 1023) / 1024);

    size_t tbl_bytes = (size_t)n_nodes * (2 * HIDDEN * sizeof(float) + 2 * ZPAD * sizeof(unsigned short));
    size_t rec_bytes = (size_t)n_edges * sizeof(int4);

    auto al = [](size_t x) { return (x + 255) & ~(size_t)255; };
    size_t need_new = al(m * 4) + al((m + 1) * 4) + al(2048 * 4) +
                      al((size_t)(n_nodes + 1) * 4) + al(rec_bytes) +
                      al(rec_bytes > tbl_bytes ? rec_bytes : tbl_bytes);

    char* ws = (char*)d_ws;
    size_t o = 0;
    auto alloc = [&](size_t bytes) { char* p = ws + o; o = (o + bytes + 255) & ~(size_t)255; return p; };

    if (nbuck <= MAXBUCK && scanb_m <= 1024 && n_nodes <= (1 << 24) && ws_size >= need_new) {
        // ---- bucketed LDS-atomic CSR build + 1-lane-per-node batched gather ----
        int*  hist     = (int*)alloc(m * 4);
        int*  base     = (int*)alloc((m + 1) * 4);
        int*  partials = (int*)alloc(2048 * 4);
        int*  offsets  = (int*)alloc((size_t)(n_nodes + 1) * 4);
        int4* rec_b    = (int4*)alloc(rec_bytes);  // final sorted CSR, lives whole pipeline
        char* ovl      = alloc(rec_bytes > tbl_bytes ? rec_bytes : tbl_bytes);
        int4* rec_a    = (int4*)ovl;               // dead after bucket_csr
        float*          h0 = (float*)ovl;          // overlays rec_a after P3
        float*          h1 = h0 + (size_t)n_nodes * HIDDEN;
        unsigned short* z0 = (unsigned short*)(h1 + (size_t)n_nodes * HIDDEN);
        unsigned short* z1 = z0 + (size_t)n_nodes * ZPAD;

        hist_kernel<<<NB2, 512, 0, stream>>>(dst, hist, n_edges, nbuck);
        scan_block_sums<<<scanb_m, 1024, 0, stream>>>(hist, partials, (int)m);
        scan_partials<<<1, 1024, 0, stream>>>(partials, scanb_m);
        scan_final<<<scanb_m, 1024, 0, stream>>>(hist, partials, base, (int)m);
        part_scatter_kernel<<<NB2, 512, 0, stream>>>(src, dst, edge_feat, base, rec_a,
                                                     n_edges, nbuck);
        bucket_csr_kernel<<<nbuck, 256, 0, stream>>>(base, rec_a, rec_b, offsets, n_nodes);

        embed_kernel<<<node_blocks, TB, 0, stream>>>(vertex, w_init, gw, h0, z0, n_nodes);
        gather_update_kernel<<<gu_blocks, 256, 0, stream>>>(h0, z0, rec_b, offsets, gw, uw,
                                                            h1, z1, n_nodes, 1, 0x00ffffffu);
        gather_update_kernel<<<gu_blocks, 256, 0, stream>>>(h1, z1, rec_b, offsets, gw, uw,
                                                            out, z0, n_nodes, 0, 0x00ffffffu);
    } else {
        // ---- fallback: global-atomic CSR build + same gather ----
        int*  counts   = (int*)alloc((size_t)(n_nodes + 1) * 4);
        int*  offsets  = (int*)alloc((size_t)(n_nodes + 1) * 4);
        int*  partials = (int*)alloc(2048 * 4);
        int4* rec      = (int4*)alloc(rec_bytes);
        size_t pos_bytes = (size_t)n_edges * sizeof(unsigned short);
        char* overlay = alloc(pos_bytes > tbl_bytes ? pos_bytes : tbl_bytes);
        unsigned short* pos = (unsigned short*)overlay;
        float*          h0  = (float*)overlay;
        float*          h1  = h0 + (size_t)n_nodes * HIDDEN;
        unsigned short* z0  = (unsigned short*)(h1 + (size_t)n_nodes * HIDDEN);
        unsigned short* z1  = z0 + (size_t)n_nodes * ZPAD;

        const int edge_blocks = (int)((n_edges + TB - 1) / TB);
        const int cp_blocks   = (int)((n_edges / 4 + TB - 1) / TB);
        const int scan_blocks = (n_nodes + 1 + 1023) / 1024;

        hipMemsetAsync(counts, 0, (size_t)(n_nodes + 1) * 4, stream);
        count_pos_kernel<<<cp_blocks, TB, 0, stream>>>(dst, counts, pos, n_edges);
        scan_block_sums<<<scan_blocks, 1024, 0, stream>>>(counts, partials, n_nodes);
        scan_partials<<<1, 1024, 0, stream>>>(partials, scan_blocks);
        scan_final<<<scan_blocks, 1024, 0, stream>>>(counts, partials, offsets, n_nodes);
        scatter_rec_kernel<<<edge_blocks, TB, 0, stream>>>(src, dst, edge_feat, pos, offsets,
                                                           rec, n_edges);
        embed_kernel<<<node_blocks, TB, 0, stream>>>(vertex, w_init, gw, h0, z0, n_nodes);
        gather_update_kernel<<<gu_blocks, 256, 0, stream>>>(h0, z0, rec, offsets, gw, uw,
                                                            h1, z1, n_nodes, 1, 0xffffffffu);
        gather_update_kernel<<<gu_blocks, 256, 0, stream>>>(h1, z1, rec, offsets, gw, uw,
                                                            out, z0, n_nodes, 0, 0xffffffffu);
    }
    (void)ws_size;
}

// Round 6
// 732.188 us; speedup vs baseline: 1.1650x; 1.1650x over previous
//
#include <hip/hip_runtime.h>

#define ATOMF 82
#define EDGE_DIM 6
#define HIDDEN 10
#define ZPAD 16  // z row = 10 bf16 + 6 pad = 32 B

// bucketed CSR build parameters
#define BSHIFT 8          // 256 nodes per bucket
#define BUCKN (1 << BSHIFT)
#define MAXBUCK 1024      // fast path supports n_nodes <= 262144 (and <= 2^24 for packing)
#define NB2 256           // partition blocks: open write-lines/XCD ~ 1.6MB < 4MB L2
#define MAXE3 16384       // per-bucket edge capacity for LDS lid cache

__device__ __forceinline__ float lrelu(float x) { return x > 0.f ? x : 0.1f * x; }

__device__ __forceinline__ unsigned int f2bf(float f) {
    unsigned int u = __float_as_uint(f);
    return (u + 0x7fffu + ((u >> 16) & 1u)) >> 16;  // RNE
}
__device__ __forceinline__ float bf2f(unsigned int b) {
    return __uint_as_float(b << 16);
}

typedef float vf2 __attribute__((ext_vector_type(2)));
__device__ __forceinline__ int nt_i(const int* p) { return __builtin_nontemporal_load(p); }
__device__ __forceinline__ vf2 nt_f2(const float* p) {
    return __builtin_nontemporal_load((const vf2*)p);
}

// h[node] = lrelu(vertex[node] @ W); z[node] = bf16(h[node] @ GW_h)
__global__ void embed_kernel(const float* __restrict__ vertex,
                             const float* __restrict__ W,
                             const float* __restrict__ GW,
                             float* __restrict__ h, unsigned short* __restrict__ z,
                             int n_nodes) {
    __shared__ float w[ATOMF * HIDDEN];
    __shared__ float gwh[HIDDEN * HIDDEN];
    for (int i = threadIdx.x; i < ATOMF * HIDDEN; i += blockDim.x) w[i] = W[i];
    for (int i = threadIdx.x; i < HIDDEN * HIDDEN; i += blockDim.x) gwh[i] = GW[i];
    __syncthreads();
    int node = blockIdx.x * blockDim.x + threadIdx.x;
    if (node >= n_nodes) return;
    const float2* v = (const float2*)(vertex + (long)node * ATOMF);  // 328B rows, 8B aligned
    float acc[HIDDEN];
#pragma unroll
    for (int j = 0; j < HIDDEN; j++) acc[j] = 0.f;
#pragma unroll 2
    for (int k2 = 0; k2 < ATOMF / 2; k2++) {
        float2 t = v[k2];
#pragma unroll
        for (int j = 0; j < HIDDEN; j++) acc[j] += t.x * w[(2 * k2) * HIDDEN + j];
#pragma unroll
        for (int j = 0; j < HIDDEN; j++) acc[j] += t.y * w[(2 * k2 + 1) * HIDDEN + j];
    }
    float ho[HIDDEN];
    float* out = h + (long)node * HIDDEN;
#pragma unroll
    for (int j = 0; j < HIDDEN; j++) { ho[j] = lrelu(acc[j]); out[j] = ho[j]; }
    float zv[HIDDEN];
#pragma unroll
    for (int j = 0; j < HIDDEN; j++) zv[j] = 0.f;
#pragma unroll
    for (int k = 0; k < HIDDEN; k++) {
        float x = ho[k];
#pragma unroll
        for (int j = 0; j < HIDDEN; j++) zv[j] += x * gwh[k * HIDDEN + j];
    }
    unsigned int* zq = (unsigned int*)(z + (size_t)node * ZPAD);
    int4 pk;
    pk.x = (int)(f2bf(zv[0]) | (f2bf(zv[1]) << 16));
    pk.y = (int)(f2bf(zv[2]) | (f2bf(zv[3]) << 16));
    pk.z = (int)(f2bf(zv[4]) | (f2bf(zv[5]) << 16));
    pk.w = (int)(f2bf(zv[6]) | (f2bf(zv[7]) << 16));
    *(int4*)zq = pk;
    zq[4] = f2bf(zv[8]) | (f2bf(zv[9]) << 16);
}

// ---- P1: per-(bucket,block) histogram, LDS atomics only; nt stream reads ----
__global__ __launch_bounds__(1024) void hist_kernel(const int* __restrict__ dst,
                                                    int* __restrict__ hist,
                                                    long n_edges, int nbuck) {
    __shared__ int hl[MAXBUCK];
    for (int t = threadIdx.x; t < nbuck; t += 1024) hl[t] = 0;
    __syncthreads();
    long per = (n_edges + gridDim.x - 1) / gridDim.x;
    long s = (long)blockIdx.x * per;
    long e = s + per; if (e > n_edges) e = n_edges;
    for (long i = s + threadIdx.x; i < e; i += 1024)
        atomicAdd(&hl[nt_i(dst + i) >> BSHIFT], 1);
    __syncthreads();
    for (int t = threadIdx.x; t < nbuck; t += 1024)
        hist[(size_t)t * gridDim.x + blockIdx.x] = hl[t];
}

// ---- generic device-wide exclusive scan: in[0..n-1] -> out[0..n] ----
__global__ __launch_bounds__(1024) void scan_block_sums(const int* __restrict__ in,
                                                        int* __restrict__ partials, int n) {
    __shared__ int ws[16];
    int i = blockIdx.x * 1024 + threadIdx.x;
    int v = (i < n) ? in[i] : 0;
    int lane = threadIdx.x & 63, wid = threadIdx.x >> 6;
    int s = v;
#pragma unroll
    for (int off = 32; off > 0; off >>= 1) s += __shfl_down(s, off, 64);
    if (lane == 0) ws[wid] = s;
    __syncthreads();
    if (threadIdx.x == 0) {
        int t = 0;
#pragma unroll
        for (int k = 0; k < 16; k++) t += ws[k];
        partials[blockIdx.x] = t;
    }
}
__global__ __launch_bounds__(1024) void scan_partials(int* __restrict__ partials, int nb) {
    __shared__ int wsum[16];
    int lane = threadIdx.x & 63, wid = threadIdx.x >> 6;
    int v = (threadIdx.x < nb) ? partials[threadIdx.x] : 0;
    int incl = v;
#pragma unroll
    for (int off = 1; off < 64; off <<= 1) {
        int t = __shfl_up(incl, off, 64);
        if (lane >= off) incl += t;
    }
    if (lane == 63) wsum[wid] = incl;
    __syncthreads();
    if (wid == 0 && lane < 16) {
        int wv = wsum[lane];
        int wincl = wv;
#pragma unroll
        for (int off = 1; off < 16; off <<= 1) {
            int t = __shfl_up(wincl, off, 64);
            if (lane >= off) wincl += t;
        }
        wsum[lane] = wincl - wv;
    }
    __syncthreads();
    if (threadIdx.x < nb) partials[threadIdx.x] = wsum[wid] + (incl - v);
}
__global__ __launch_bounds__(1024) void scan_final(const int* __restrict__ in,
                                                   const int* __restrict__ partials,
                                                   int* __restrict__ out, int n) {
    __shared__ int wsum[16];
    int i = blockIdx.x * 1024 + threadIdx.x;
    int v = (i < n) ? in[i] : 0;
    int lane = threadIdx.x & 63, wid = threadIdx.x >> 6;
    int incl = v;
#pragma unroll
    for (int off = 1; off < 64; off <<= 1) {
        int t = __shfl_up(incl, off, 64);
        if (lane >= off) incl += t;
    }
    if (lane == 63) wsum[wid] = incl;
    __syncthreads();
    if (wid == 0 && lane < 16) {
        int wv = wsum[lane];
        int wincl = wv;
#pragma unroll
        for (int off = 1; off < 16; off <<= 1) {
            int t = __shfl_up(wincl, off, 64);
            if (lane >= off) wincl += t;
        }
        wsum[lane] = wincl - wv;
    }
    __syncthreads();
    if (i <= n) out[i] = partials[blockIdx.x] + wsum[wid] + (incl - v);
}

// ---- P2: partition edges into bucket-grouped order; LDS cursor atomics only.
// 1024 threads x 256 blocks: 16 waves/CU (grid was the occupancy limit), while the
// open-write-line working set stays per-block. Streams read non-temporally so they
// don't evict partially-filled rec write lines from L2.
// Node-local id (8 bits) packed into r.x[31:24]; requires n_nodes <= 2^24.
__global__ __launch_bounds__(1024) void part_scatter_kernel(
    const int* __restrict__ src, const int* __restrict__ dst,
    const float* __restrict__ ef, const int* __restrict__ base,
    int4* __restrict__ rec, long n_edges, int nbuck) {
    __shared__ int cur[MAXBUCK];
    for (int t = threadIdx.x; t < nbuck; t += 1024)
        cur[t] = base[(size_t)t * gridDim.x + blockIdx.x];
    __syncthreads();
    long per = (n_edges + gridDim.x - 1) / gridDim.x;
    long s = (long)blockIdx.x * per;
    long e = s + per; if (e > n_edges) e = n_edges;
    for (long i = s + threadIdx.x; i < e; i += 1024) {
        int d = nt_i(dst + i);
        int slot = atomicAdd(&cur[d >> BSHIFT], 1);  // LDS atomic
        const float* ep = ef + i * (long)EDGE_DIM;
        vf2 fa = nt_f2(ep), fb = nt_f2(ep + 2), fc = nt_f2(ep + 4);
        int4 r;
        r.x = nt_i(src + i) | ((d & (BUCKN - 1)) << 24);
        r.y = (int)(f2bf(fa.x) | (f2bf(fa.y) << 16));
        r.z = (int)(f2bf(fb.x) | (f2bf(fb.y) << 16));
        r.w = (int)(f2bf(fc.x) | (f2bf(fc.y) << 16));
        rec[slot] = r;
    }
}

// ---- P3: per-bucket node sort: count+scan in LDS, permute rec_a -> rec_b (keeps
// packed l byte), write per-node offsets. Bucket span ~128KB -> permute re-read is L2-hit.
__global__ __launch_bounds__(512) void bucket_csr_kernel(
    const int* __restrict__ base, const int4* __restrict__ rec_a, int4* __restrict__ rec_b,
    int* __restrict__ offsets, int n_nodes) {
    __shared__ unsigned char lid[MAXE3];
    __shared__ int cnt[BUCKN];
    __shared__ int excl_s[BUCKN];
    __shared__ int cursor[BUCKN];
    int b = blockIdx.x;
    int S = base[(size_t)b * NB2];
    int E = base[(size_t)(b + 1) * NB2];
    int node0 = b << BSHIFT;
    int nn = n_nodes - node0; if (nn > BUCKN) nn = BUCKN;
    if ((int)threadIdx.x < BUCKN) cnt[threadIdx.x] = 0;
    __syncthreads();
    int ne = E - S;
    bool fit = (ne <= MAXE3);
    for (int i = threadIdx.x; i < ne; i += 512) {
        int l = (int)((unsigned int)rec_a[S + i].x >> 24);
        if (fit) lid[i] = (unsigned char)l;
        atomicAdd(&cnt[l], 1);
    }
    __syncthreads();
    if (threadIdx.x == 0) {
        int run = 0;
#pragma unroll 4
        for (int l = 0; l < BUCKN; l++) { excl_s[l] = run; run += cnt[l]; }
    }
    __syncthreads();
    if ((int)threadIdx.x < nn) offsets[node0 + threadIdx.x] = S + excl_s[threadIdx.x];
    if ((int)threadIdx.x < BUCKN) cursor[threadIdx.x] = excl_s[threadIdx.x];
    if (b == (int)gridDim.x - 1 && threadIdx.x == 0) offsets[n_nodes] = E;
    __syncthreads();
    for (int i = threadIdx.x; i < ne; i += 512) {
        int4 r = rec_a[S + i];  // L2-resident re-read
        int l = fit ? (int)lid[i] : (int)((unsigned int)r.x >> 24);
        int q = atomicAdd(&cursor[l], 1);  // LDS atomic
        rec_b[S + q] = r;
    }
}

// ---- fallback path (small workspace / huge n_nodes): global-atomic rank ----
__global__ void count_pos_kernel(const int* __restrict__ dst, int* __restrict__ counts,
                                 unsigned short* __restrict__ pos, long n_edges) {
    long e0 = ((long)blockIdx.x * blockDim.x + threadIdx.x) * 4;
    if (e0 + 3 < n_edges) {
        int4 d = *(const int4*)(dst + e0);
        ushort4 p;
        p.x = (unsigned short)atomicAdd(&counts[d.x], 1);
        p.y = (unsigned short)atomicAdd(&counts[d.y], 1);
        p.z = (unsigned short)atomicAdd(&counts[d.z], 1);
        p.w = (unsigned short)atomicAdd(&counts[d.w], 1);
        *(ushort4*)(pos + e0) = p;
    } else {
        for (long e = e0; e < n_edges; e++)
            pos[e] = (unsigned short)atomicAdd(&counts[dst[e]], 1);
    }
}
__global__ void scatter_rec_kernel(const int* __restrict__ src, const int* __restrict__ dst,
                                   const float* __restrict__ ef,
                                   const unsigned short* __restrict__ pos,
                                   const int* __restrict__ offsets,
                                   int4* __restrict__ rec, long n_edges) {
    long e = (long)blockIdx.x * blockDim.x + threadIdx.x;
    if (e >= n_edges) return;
    int d = dst[e];
    int q = offsets[d] + (int)pos[e];
    const float2* er = (const float2*)(ef + e * (long)EDGE_DIM);
    float2 fa = er[0], fb = er[1], fc = er[2];
    int4 r;
    r.x = src[e];
    r.y = (int)(f2bf(fa.x) | (f2bf(fa.y) << 16));
    r.z = (int)(f2bf(fb.x) | (f2bf(fb.y) << 16));
    r.w = (int)(f2bf(fc.x) | (f2bf(fc.y) << 16));
    rec[q] = r;
}

// 16 lanes per dst node: stream CSR records, gather bf16 z (1 sector/edge),
// msg = lrelu(z[src] + ef@GW_e); fused update GEMV + next-layer z epilogue.
// src_mask strips the packed node-local byte on the fast path.
__global__ __launch_bounds__(256) void gather_update_kernel(
    const float* __restrict__ h_in, const unsigned short* __restrict__ z_in,
    const int4* __restrict__ rec, const int* __restrict__ offsets,
    const float* __restrict__ GW, const float* __restrict__ UW,
    float* __restrict__ h_out, unsigned short* __restrict__ z_out,
    int n_nodes, int write_z, unsigned int src_mask) {
    __shared__ float gwh[HIDDEN * HIDDEN];    // GW rows 0..9  (h part)
    __shared__ float gwe[EDGE_DIM * HIDDEN];  // GW rows 10..15 (ef part)
    __shared__ float uw[2 * HIDDEN * HIDDEN];
    for (int i = threadIdx.x; i < HIDDEN * HIDDEN; i += 256) gwh[i] = GW[i];
    for (int i = threadIdx.x; i < EDGE_DIM * HIDDEN; i += 256) gwe[i] = GW[HIDDEN * HIDDEN + i];
    for (int i = threadIdx.x; i < 2 * HIDDEN * HIDDEN; i += 256) uw[i] = UW[i];
    __syncthreads();
    int group = threadIdx.x >> 4;  // 16 nodes per block
    int sub = threadIdx.x & 15;
    int node = blockIdx.x * 16 + group;
    if (node >= n_nodes) return;
    int off0 = offsets[node], off1 = offsets[node + 1];
    float acc[HIDDEN];
#pragma unroll
    for (int j = 0; j < HIDDEN; j++) acc[j] = 0.f;
    int p = off0 + sub;
    int4 r;
    if (p < off1) r = rec[p];
    while (p < off1) {
        int pn = p + 16;
        int4 rn = r;
        if (pn < off1) rn = rec[pn];  // prefetch next record over current z latency
        int sn = (int)((unsigned int)r.x & src_mask);
        const int* zq = (const int*)(z_in + (size_t)sn * ZPAD);
        int4 za = *(const int4*)zq;
        int zb = zq[4];
        float ef[EDGE_DIM];
        unsigned int u0 = (unsigned int)r.y, u1 = (unsigned int)r.z, u2 = (unsigned int)r.w;
        ef[0] = bf2f(u0 & 0xffffu); ef[1] = bf2f(u0 >> 16);
        ef[2] = bf2f(u1 & 0xffffu); ef[3] = bf2f(u1 >> 16);
        ef[4] = bf2f(u2 & 0xffffu); ef[5] = bf2f(u2 >> 16);
        float m[HIDDEN];
#pragma unroll
        for (int j = 0; j < HIDDEN; j++) m[j] = 0.f;
#pragma unroll
        for (int k = 0; k < EDGE_DIM; k++) {
            float x = ef[k];
#pragma unroll
            for (int j = 0; j < HIDDEN; j++) m[j] += x * gwe[k * HIDDEN + j];
        }
        unsigned int z0 = (unsigned int)za.x, z1 = (unsigned int)za.y;
        unsigned int z2 = (unsigned int)za.z, z3 = (unsigned int)za.w, z4 = (unsigned int)zb;
        acc[0] += lrelu(m[0] + bf2f(z0 & 0xffffu));
        acc[1] += lrelu(m[1] + bf2f(z0 >> 16));
        acc[2] += lrelu(m[2] + bf2f(z1 & 0xffffu));
        acc[3] += lrelu(m[3] + bf2f(z1 >> 16));
        acc[4] += lrelu(m[4] + bf2f(z2 & 0xffffu));
        acc[5] += lrelu(m[5] + bf2f(z2 >> 16));
        acc[6] += lrelu(m[6] + bf2f(z3 & 0xffffu));
        acc[7] += lrelu(m[7] + bf2f(z3 >> 16));
        acc[8] += lrelu(m[8] + bf2f(z4 & 0xffffu));
        acc[9] += lrelu(m[9] + bf2f(z4 >> 16));
        r = rn; p = pn;
    }
#pragma unroll
    for (int j = 0; j < HIDDEN; j++) {
#pragma unroll
        for (int d = 8; d > 0; d >>= 1) acc[j] += __shfl_down(acc[j], d, 16);
    }
    if (sub == 0) {
        float in[2 * HIDDEN];
        const float2* hp = (const float2*)(h_in + (long)node * HIDDEN);
#pragma unroll
        for (int k = 0; k < 5; k++) { float2 t = hp[k]; in[2 * k] = t.x; in[2 * k + 1] = t.y; }
#pragma unroll
        for (int j = 0; j < HIDDEN; j++) in[HIDDEN + j] = acc[j];
        float o[HIDDEN];
#pragma unroll
        for (int j = 0; j < HIDDEN; j++) o[j] = 0.f;
#pragma unroll
        for (int k = 0; k < 2 * HIDDEN; k++) {
            float x = in[k];
#pragma unroll
            for (int j = 0; j < HIDDEN; j++) o[j] += x * uw[k * HIDDEN + j];
        }
        float ho[HIDDEN];
        float* outp = h_out + (long)node * HIDDEN;
#pragma unroll
        for (int j = 0; j < HIDDEN; j++) { ho[j] = lrelu(o[j]); outp[j] = ho[j]; }
        if (write_z) {
            float zv[HIDDEN];
#pragma unroll
            for (int j = 0; j < HIDDEN; j++) zv[j] = 0.f;
#pragma unroll
            for (int k = 0; k < HIDDEN; k++) {
                float x = ho[k];
#pragma unroll
                for (int j = 0; j < HIDDEN; j++) zv[j] += x * gwh[k * HIDDEN + j];
            }
            unsigned int* zq = (unsigned int*)(z_out + (size_t)node * ZPAD);
            int4 pk;
            pk.x = (int)(f2bf(zv[0]) | (f2bf(zv[1]) << 16));
            pk.y = (int)(f2bf(zv[2]) | (f2bf(zv[3]) << 16));
            pk.z = (int)(f2bf(zv[4]) | (f2bf(zv[5]) << 16));
            pk.w = (int)(f2bf(zv[6]) | (f2bf(zv[7]) << 16));
            *(int4*)zq = pk;
            zq[4] = f2bf(zv[8]) | (f2bf(zv[9]) << 16);
        }
    }
}

extern "C" void kernel_launch(void* const* d_in, const int* in_sizes, int n_in,
                              void* d_out, int out_size, void* d_ws, size_t ws_size,
                              hipStream_t stream) {
    const float* vertex    = (const float*)d_in[0];
    const float* edge_feat = (const float*)d_in[1];
    const int*   src       = (const int*)d_in[2];
    const int*   dst       = (const int*)d_in[3];
    const float* w_init    = (const float*)d_in[4];
    const float* gw        = (const float*)d_in[5];
    const float* uw        = (const float*)d_in[6];

    const int  n_nodes = in_sizes[0] / ATOMF;
    const long n_edges = (long)in_sizes[2];
    float* out = (float*)d_out;

    const int TB = 256;
    const int node_blocks = (n_nodes + TB - 1) / TB;
    const int gu_blocks   = (n_nodes + 15) / 16;

    const int nbuck = (n_nodes + BUCKN - 1) >> BSHIFT;
    const long m = (long)nbuck * NB2;
    const int scanb_m = (int)((m + 1 + 1023) / 1024);

    size_t tbl_bytes = (size_t)n_nodes * (2 * HIDDEN * sizeof(float) + 2 * ZPAD * sizeof(unsigned short));
    size_t rec_bytes = (size_t)n_edges * sizeof(int4);

    auto al = [](size_t x) { return (x + 255) & ~(size_t)255; };
    size_t need_new = al(m * 4) + al((m + 1) * 4) + al(2048 * 4) +
                      al((size_t)(n_nodes + 1) * 4) + al(rec_bytes) +
                      al(rec_bytes > tbl_bytes ? rec_bytes : tbl_bytes);

    char* ws = (char*)d_ws;
    size_t o = 0;
    auto alloc = [&](size_t bytes) { char* p = ws + o; o = (o + bytes + 255) & ~(size_t)255; return p; };

    if (nbuck <= MAXBUCK && scanb_m <= 1024 && n_nodes <= (1 << 24) && ws_size >= need_new) {
        // ---- bucketed LDS-atomic CSR build + 16-lane CSR gather ----
        int*  hist     = (int*)alloc(m * 4);
        int*  base     = (int*)alloc((m + 1) * 4);
        int*  partials = (int*)alloc(2048 * 4);
        int*  offsets  = (int*)alloc((size_t)(n_nodes + 1) * 4);
        int4* rec_b    = (int4*)alloc(rec_bytes);  // final sorted CSR, lives whole pipeline
        char* ovl      = alloc(rec_bytes > tbl_bytes ? rec_bytes : tbl_bytes);
        int4* rec_a    = (int4*)ovl;               // dead after bucket_csr
        float*          h0 = (float*)ovl;          // overlays rec_a after P3
        float*          h1 = h0 + (size_t)n_nodes * HIDDEN;
        unsigned short* z0 = (unsigned short*)(h1 + (size_t)n_nodes * HIDDEN);
        unsigned short* z1 = z0 + (size_t)n_nodes * ZPAD;

        hist_kernel<<<NB2, 1024, 0, stream>>>(dst, hist, n_edges, nbuck);
        scan_block_sums<<<scanb_m, 1024, 0, stream>>>(hist, partials, (int)m);
        scan_partials<<<1, 1024, 0, stream>>>(partials, scanb_m);
        scan_final<<<scanb_m, 1024, 0, stream>>>(hist, partials, base, (int)m);
        part_scatter_kernel<<<NB2, 1024, 0, stream>>>(src, dst, edge_feat, base, rec_a,
                                                      n_edges, nbuck);
        bucket_csr_kernel<<<nbuck, 512, 0, stream>>>(base, rec_a, rec_b, offsets, n_nodes);

        embed_kernel<<<node_blocks, TB, 0, stream>>>(vertex, w_init, gw, h0, z0, n_nodes);
        gather_update_kernel<<<gu_blocks, TB, 0, stream>>>(h0, z0, rec_b, offsets, gw, uw,
                                                           h1, z1, n_nodes, 1, 0x00ffffffu);
        gather_update_kernel<<<gu_blocks, TB, 0, stream>>>(h1, z1, rec_b, offsets, gw, uw,
                                                           out, z0, n_nodes, 0, 0x00ffffffu);
    } else {
        // ---- fallback: global-atomic CSR build + 16-lane-per-node gather ----
        int*  counts   = (int*)alloc((size_t)(n_nodes + 1) * 4);
        int*  offsets  = (int*)alloc((size_t)(n_nodes + 1) * 4);
        int*  partials = (int*)alloc(2048 * 4);
        int4* rec      = (int4*)alloc(rec_bytes);
        size_t pos_bytes = (size_t)n_edges * sizeof(unsigned short);
        char* overlay = alloc(pos_bytes > tbl_bytes ? pos_bytes : tbl_bytes);
        unsigned short* pos = (unsigned short*)overlay;
        float*          h0  = (float*)overlay;
        float*          h1  = h0 + (size_t)n_nodes * HIDDEN;
        unsigned short* z0  = (unsigned short*)(h1 + (size_t)n_nodes * HIDDEN);
        unsigned short* z1  = z0 + (size_t)n_nodes * ZPAD;

        const int edge_blocks = (int)((n_edges + TB - 1) / TB);
        const int cp_blocks   = (int)((n_edges / 4 + TB - 1) / TB);
        const int scan_blocks = (n_nodes + 1 + 1023) / 1024;

        hipMemsetAsync(counts, 0, (size_t)(n_nodes + 1) * 4, stream);
        count_pos_kernel<<<cp_blocks, TB, 0, stream>>>(dst, counts, pos, n_edges);
        scan_block_sums<<<scan_blocks, 1024, 0, stream>>>(counts, partials, n_nodes);
        scan_partials<<<1, 1024, 0, stream>>>(partials, scan_blocks);
        scan_final<<<scan_blocks, 1024, 0, stream>>>(counts, partials, offsets, n_nodes);
        scatter_rec_kernel<<<edge_blocks, TB, 0, stream>>>(src, dst, edge_feat, pos, offsets,
                                                           rec, n_edges);
        embed_kernel<<<node_blocks, TB, 0, stream>>>(vertex, w_init, gw, h0, z0, n_nodes);
        gather_update_kernel<<<gu_blocks, TB, 0, stream>>>(h0, z0, rec, offsets, gw, uw,
                                                           h1, z1, n_nodes, 1, 0xffffffffu);
        gather_update_kernel<<<gu_blocks, TB, 0, stream>>>(h1, z1, rec, offsets, gw, uw,
                                                           out, z0, n_nodes, 0, 0xffffffffu);
    }
    (void)ws_size;
}